// Round 13
// baseline (54.327 us; speedup 1.0000x reference)
//
#include <hip/hip_runtime.h>
#include <hip/hip_bf16.h>

typedef __attribute__((ext_vector_type(8))) short short8;
typedef __attribute__((ext_vector_type(4))) float floatx4;

#define B_ROWS 8192
#define DIM    128
#define NSPLIT 16
#define JSPAN  (B_ROWS / NSPLIT)        // 512 cols per split
#define NTILE  (JSPAN / 16)             // 32 j-tiles of 16 cols
#define WAVES  4
#define RPW    64                       // rows per wave (4 x 16-row MFMA sets)
#define BM     (WAVES * RPW)            // 256 rows per block
#define NBLK   512                      // (B_ROWS/BM) * NSPLIT = 2 blocks/CU
#define BIAS   4096.0f
#define KOFF   64.0f                    // keeps atomic keys strictly positive

// Fragment-ordered buffer xf: for 16-row tile t, k-slice kk (0..3), lane l (0..63):
//   bf16 index = t*2048 + kk*512 + l*8 + e
// = element (row = t*16 + (l&15), k = kk*32 + (l>>4)*8 + e) — the exact
// mfma_f32_16x16x32_bf16 A/B fragment layout. One tile = 4KB contiguous.

// ws layout
#define OFF_SQLAB (2u << 20)                  // float2 {sq, lab_bits}[8192], 64KB
#define OFF_KP    (OFF_SQLAB + (64u << 10))   // int keys, 32KB
#define OFF_KN    (OFF_KP + (32u << 10))      // int keys, 32KB
#define OFF_ACC   (OFF_KN + (32u << 10))      // float sum, int done

// ---------------- prep: f32 -> bf16 fragment-order + packed norms/labels + init ----------------
__global__ __launch_bounds__(256) void prep_kernel(const float* __restrict__ x,
                                                   const int* __restrict__ lab,
                                                   __hip_bfloat16* __restrict__ xf,
                                                   float2* __restrict__ sqlab,
                                                   int* __restrict__ kp,
                                                   int* __restrict__ kn,
                                                   float* __restrict__ acc_sum,
                                                   int* __restrict__ done) {
    const int gid = blockIdx.x * 256 + threadIdx.x;
    if (gid < B_ROWS) { kp[gid] = 0; kn[gid] = 0x7F7F7F7F; }
    if (gid == 0) { acc_sum[0] = 0.f; done[0] = 0; }

    const int row  = blockIdx.x * 4 + (threadIdx.x >> 6);
    const int lane = threadIdx.x & 63;   // holds k = 2*lane, 2*lane+1
    const float2 v = *reinterpret_cast<const float2*>(x + row * DIM + lane * 2);
    __hip_bfloat162 b2;
    b2.x = __float2bfloat16(v.x);
    b2.y = __float2bfloat16(v.y);
    // fragment-order address for k0 = 2*lane
    const int kk = lane >> 4;
    const int g  = (lane >> 2) & 3;
    const int e  = (lane & 3) * 2;
    const int idx = (row >> 4) * 2048 + kk * 512 + (g * 16 + (row & 15)) * 8 + e;
    *reinterpret_cast<__hip_bfloat162*>(xf + idx) = b2;
    float s = v.x * v.x + v.y * v.y;
    #pragma unroll
    for (int m = 1; m < 64; m <<= 1) s += __shfl_xor(s, m, 64);
    if (lane == 0) {
        float2 p; p.x = s; p.y = __int_as_float(lab[row]);
        sqlab[row] = p;
    }
}

// ---------------- main: barrier-free Gram + hardest pos/neg + last-block combine ----------------
// 1D grid of 512; split = id & 15 so id%8 = split%8 -> all 32 row-blocks of a
// split land on one XCD (panel L2 reuse). Wave owns 64 rows; streams 32 B-tiles
// via DEPTH-3 named register prefetch (load->use distance ~2 STEPs), immediate
// max/min merge. key = sq_j - 2*dot + BIAS*same (+sq_i+KOFF at flush).
// Outputs via idempotent atomicMax/Min int-punned keys; last block reduces.
__global__ __launch_bounds__(256, 2) void main_kernel(
    const __hip_bfloat16* __restrict__ xf,
    const float2* __restrict__ sqlab,
    int* __restrict__ kp,
    int* __restrict__ kn,
    float* __restrict__ acc_sum,
    int* __restrict__ done,
    float* __restrict__ out) {
    const int tid  = threadIdx.x;
    const int lane = tid & 63;
    const int wave = tid >> 6;
    const int l15  = lane & 15;
    const int g    = lane >> 4;
    const int b    = blockIdx.x;
    const int rowbase = (b >> 4) * BM + wave * RPW;
    const int jstart  = (b & 15) * JSPAN;

    // A fragments: 4 sets x 16 rows, contiguous loads from xf
    short8 a[4][4];
    #pragma unroll
    for (int s = 0; s < 4; ++s) {
        const __hip_bfloat16* ap = xf + ((size_t)(rowbase >> 4) + s) * 2048 + lane * 8;
        #pragma unroll
        for (int kk = 0; kk < 4; ++kk)
            a[s][kk] = *reinterpret_cast<const short8*>(ap + kk * 512);
    }
    int labi[4][4];
    #pragma unroll
    for (int s = 0; s < 4; ++s)
        #pragma unroll
        for (int q = 0; q < 4; ++q)
            labi[s][q] = __float_as_int(sqlab[rowbase + s * 16 + g * 4 + q].y);

    float mx[4][4], mn[4][4];
    #pragma unroll
    for (int s = 0; s < 4; ++s)
        #pragma unroll
        for (int q = 0; q < 4; ++q) { mx[s][q] = -INFINITY; mn[s][q] = INFINITY; }

    const __hip_bfloat16* bbase = xf + (size_t)(jstart >> 4) * 2048 + lane * 8;

    short8 b0[4], b1[4], b2[4];
    float2 sl0, sl1, sl2;

    #define LOADT(BB, SL, T)                                                   \
    do {                                                                       \
        const __hip_bfloat16* bp_ = bbase + (size_t)(T) * 2048;                \
        _Pragma("unroll")                                                      \
        for (int kk = 0; kk < 4; ++kk)                                         \
            BB[kk] = *reinterpret_cast<const short8*>(bp_ + kk * 512);         \
        SL = sqlab[jstart + (T) * 16 + l15];                                   \
    } while (0)

    #define STEP(BB, SL)                                                       \
    do {                                                                       \
        floatx4 acc[4];                                                        \
        _Pragma("unroll")                                                      \
        for (int s = 0; s < 4; ++s) acc[s] = (floatx4){0.f, 0.f, 0.f, 0.f};    \
        _Pragma("unroll")                                                      \
        for (int kk = 0; kk < 4; ++kk) {                                       \
            _Pragma("unroll")                                                  \
            for (int s = 0; s < 4; ++s)                                        \
                acc[s] = __builtin_amdgcn_mfma_f32_16x16x32_bf16(a[s][kk], BB[kk], acc[s], 0, 0, 0); \
        }                                                                      \
        const float sqj  = (SL).x;                                             \
        const int   labj = __float_as_int((SL).y);                             \
        const float sqjb = sqj + BIAS;                                         \
        _Pragma("unroll")                                                      \
        for (int s = 0; s < 4; ++s) {                                          \
            _Pragma("unroll")                                                  \
            for (int q = 0; q < 4; ++q) {                                      \
                const float t_ = fmaf(-2.f, acc[s][q],                         \
                                      (labj == labi[s][q]) ? sqjb : sqj);      \
                mx[s][q] = fmaxf(mx[s][q], t_);                                \
                mn[s][q] = fminf(mn[s][q], t_);                                \
            }                                                                  \
        }                                                                      \
    } while (0)

    // prologue: fill depth-3 ring
    LOADT(b0, sl0, 0);
    LOADT(b1, sl1, 1);
    LOADT(b2, sl2, 2);

    for (int jt = 0; jt < NTILE; jt += 3) {
        STEP(b0, sl0);
        if (jt + 3 < NTILE) LOADT(b0, sl0, jt + 3);
        if (jt + 1 < NTILE) {
            STEP(b1, sl1);
            if (jt + 4 < NTILE) LOADT(b1, sl1, jt + 4);
        }
        if (jt + 2 < NTILE) {
            STEP(b2, sl2);
            if (jt + 5 < NTILE) LOADT(b2, sl2, jt + 5);
        }
    }
    #undef STEP
    #undef LOADT

    // reduce over the 16 cols held by the 16 lanes of each g-group
    #pragma unroll
    for (int s = 0; s < 4; ++s)
        #pragma unroll
        for (int q = 0; q < 4; ++q) {
            #pragma unroll
            for (int mk = 1; mk < 16; mk <<= 1) {
                mx[s][q] = fmaxf(mx[s][q], __shfl_xor(mx[s][q], mk, 64));
                mn[s][q] = fminf(mn[s][q], __shfl_xor(mn[s][q], mk, 64));
            }
        }
    if (l15 == 0) {
        #pragma unroll
        for (int s = 0; s < 4; ++s)
            #pragma unroll
            for (int q = 0; q < 4; ++q) {
                const int i = rowbase + s * 16 + g * 4 + q;
                const float sqi = sqlab[i].x;
                atomicMax(&kp[i], __float_as_int(sqi + mx[s][q] + KOFF));
                atomicMin(&kn[i], __float_as_int(sqi + mn[s][q] + KOFF));
            }
    }

    // ---- last-block combine (done-counter; atomic reads are device-coherent) ----
    __shared__ int isLast;
    __shared__ float sv[4];
    if (tid == 0) {
        __threadfence();
        isLast = (atomicAdd(done, 1) == NBLK - 1);
    }
    __syncthreads();
    if (!isLast) return;

    float sum = 0.f;
    for (int r = tid; r < B_ROWS; r += 256) {
        const float hp2 = __int_as_float(atomicMax(&kp[r], 0)) - BIAS - KOFF;
        const float hn2 = __int_as_float(atomicMin(&kn[r], 0x7F7F7F7F)) - KOFF;
        sum += fmaxf(sqrtf(fmaxf(hp2, 0.f)) - sqrtf(fmaxf(hn2, 0.f)) + 1.0f, 0.f);
    }
    #pragma unroll
    for (int mk = 1; mk < 64; mk <<= 1) sum += __shfl_xor(sum, mk, 64);
    if (lane == 0) sv[wave] = sum;
    __syncthreads();
    if (tid == 0) out[0] = (sv[0] + sv[1] + sv[2] + sv[3]) / (float)B_ROWS;
}

// ---------------- launch ----------------
extern "C" void kernel_launch(void* const* d_in, const int* in_sizes, int n_in,
                              void* d_out, int out_size, void* d_ws, size_t ws_size,
                              hipStream_t stream) {
    const float* x   = (const float*)d_in[0];
    const int*   lab = (const int*)d_in[1];
    float*       out = (float*)d_out;

    char* ws = (char*)d_ws;
    __hip_bfloat16* xf = (__hip_bfloat16*)ws;
    float2* sqlab   = (float2*)(ws + OFF_SQLAB);
    int*    kp      = (int*)(ws + OFF_KP);
    int*    kn      = (int*)(ws + OFF_KN);
    float*  acc_sum = (float*)(ws + OFF_ACC);
    int*    done    = (int*)(ws + OFF_ACC + 4);

    prep_kernel<<<B_ROWS / 4, 256, 0, stream>>>(x, lab, xf, sqlab, kp, kn, acc_sum, done);
    main_kernel<<<NBLK, 256, 0, stream>>>(xf, sqlab, kp, kn, acc_sum, done, out);
}

// Round 14
// 50.259 us; speedup vs baseline: 1.0809x; 1.0809x over previous
//
#include <hip/hip_runtime.h>
#include <hip/hip_bf16.h>

typedef __attribute__((ext_vector_type(8))) short short8;
typedef __attribute__((ext_vector_type(4))) float floatx4;

#define B_ROWS 8192
#define DIM    128
#define NSPLIT 16
#define JSPAN  (B_ROWS / NSPLIT)        // 512 cols per split
#define NTILE  (JSPAN / 16)             // 32 j-tiles of 16 cols
#define WAVES  4
#define RPW    64                       // rows per wave (4 x 16-row MFMA sets)
#define BM     (WAVES * RPW)            // 256 rows per block
#define NRB    (B_ROWS / BM)            // 32 row-blocks
#define NBLK   (NRB * NSPLIT)           // 512 blocks = 2/CU
#define BIAS   4096.0f
#define KOFF   64.0f                    // keeps atomic keys strictly positive

// Fragment-ordered buffer xf: for 16-row tile t, k-slice kk (0..3), lane l (0..63):
//   bf16 index = t*2048 + kk*512 + l*8 + e
// = element (row = t*16 + (l&15), k = kk*32 + (l>>4)*8 + e) — the exact
// mfma_f32_16x16x32_bf16 A/B fragment layout. One tile = 4KB contiguous.

// ws layout
#define OFF_SQ  (2u << 20)                 // after 2MB xf
#define OFF_KP  (OFF_SQ + (64u << 10))     // int keys, 32KB
#define OFF_KN  (OFF_KP + (32u << 10))     // int keys, 32KB
#define OFF_ACC (OFF_KN + (32u << 10))     // int done

// ---------------- prep: f32 -> bf16 fragment-order + norms + key/ctr init ----------------
__global__ __launch_bounds__(256) void prep_kernel(const float* __restrict__ x,
                                                   __hip_bfloat16* __restrict__ xf,
                                                   float* __restrict__ sq,
                                                   int* __restrict__ kp,
                                                   int* __restrict__ kn,
                                                   int* __restrict__ done) {
    const int gid = blockIdx.x * 256 + threadIdx.x;
    if (gid < B_ROWS) { kp[gid] = 0; kn[gid] = 0x7F7F7F7F; }
    if (gid == 0) done[0] = 0;

    const int row  = blockIdx.x * 4 + (threadIdx.x >> 6);
    const int lane = threadIdx.x & 63;   // holds k = 2*lane, 2*lane+1
    const float2 v = *reinterpret_cast<const float2*>(x + row * DIM + lane * 2);
    __hip_bfloat162 b2;
    b2.x = __float2bfloat16(v.x);
    b2.y = __float2bfloat16(v.y);
    // fragment-order address for k0 = 2*lane
    const int kk = lane >> 4;
    const int g  = (lane >> 2) & 3;
    const int e  = (lane & 3) * 2;
    const int idx = (row >> 4) * 2048 + kk * 512 + (g * 16 + (row & 15)) * 8 + e;
    *reinterpret_cast<__hip_bfloat162*>(xf + idx) = b2;
    float s = v.x * v.x + v.y * v.y;
    #pragma unroll
    for (int m = 1; m < 64; m <<= 1) s += __shfl_xor(s, m, 64);
    if (lane == 0) sq[row] = s;
}

// ---------------- main: R10-exact loop + atomic keys + last-block combine ----------------
// grid = (NRB, NSPLIT), block = 256 (4 independent waves), 2 blocks/CU.
// Wave owns 64 rows; streams the split's 32 B-tiles via depth-2 named register
// prefetch, barrier-free. t = sq_j - 2*dot + BIAS*same; merge via max3/min3.
// Flush: idempotent atomicMax/Min on int-punned positive keys. Last block
// (done-counter) reduces the 8192 rows to the scalar loss.
__global__ __launch_bounds__(256, 2) void main_kernel(
    const __hip_bfloat16* __restrict__ xf,
    const float* __restrict__ sq,
    const int*  __restrict__ lab,
    int* __restrict__ kp,
    int* __restrict__ kn,
    int* __restrict__ done,
    float* __restrict__ out) {
    const int tid  = threadIdx.x;
    const int lane = tid & 63;
    const int wave = tid >> 6;
    const int l15  = lane & 15;
    const int g    = lane >> 4;
    const int rowbase = blockIdx.x * BM + wave * RPW;
    const int jstart  = blockIdx.y * JSPAN;

    // A fragments: 4 sets x 16 rows, contiguous loads from xf
    short8 a[4][4];
    #pragma unroll
    for (int s = 0; s < 4; ++s) {
        const __hip_bfloat16* ap = xf + ((size_t)(rowbase >> 4) + s) * 2048 + lane * 8;
        #pragma unroll
        for (int kk = 0; kk < 4; ++kk)
            a[s][kk] = *reinterpret_cast<const short8*>(ap + kk * 512);
    }
    int labi[4][4];
    #pragma unroll
    for (int s = 0; s < 4; ++s)
        #pragma unroll
        for (int q = 0; q < 4; ++q)
            labi[s][q] = lab[rowbase + s * 16 + g * 4 + q];

    float mx[4][4], mn[4][4];
    #pragma unroll
    for (int s = 0; s < 4; ++s)
        #pragma unroll
        for (int q = 0; q < 4; ++q) { mx[s][q] = -INFINITY; mn[s][q] = INFINITY; }

    const __hip_bfloat16* bbase = xf + (size_t)(jstart >> 4) * 2048 + lane * 8;

    short8 bA[4], bB[4];
    float sqA, sqB; int labA, labB;
    #pragma unroll
    for (int kk = 0; kk < 4; ++kk) {
        bA[kk] = *reinterpret_cast<const short8*>(bbase + kk * 512);
        bB[kk] = *reinterpret_cast<const short8*>(bbase + 2048 + kk * 512);
    }
    sqA  = sq[jstart + l15];          labA = lab[jstart + l15];
    sqB  = sq[jstart + 16 + l15];     labB = lab[jstart + 16 + l15];

    float tA[4][4], tB[4][4];

    #define MFMA_TILE(BB, T, SQJ, LABJ)                                         \
    do {                                                                        \
        floatx4 acc[4];                                                         \
        _Pragma("unroll")                                                       \
        for (int s = 0; s < 4; ++s) acc[s] = (floatx4){0.f, 0.f, 0.f, 0.f};     \
        _Pragma("unroll")                                                       \
        for (int kk = 0; kk < 4; ++kk) {                                        \
            _Pragma("unroll")                                                   \
            for (int s = 0; s < 4; ++s)                                         \
                acc[s] = __builtin_amdgcn_mfma_f32_16x16x32_bf16(a[s][kk], BB[kk], acc[s], 0, 0, 0); \
        }                                                                       \
        const float sqjb = (SQJ) + BIAS;                                        \
        _Pragma("unroll")                                                       \
        for (int s = 0; s < 4; ++s) {                                           \
            _Pragma("unroll")                                                   \
            for (int q = 0; q < 4; ++q)                                         \
                T[s][q] = fmaf(-2.f, acc[s][q], ((LABJ) == labi[s][q]) ? sqjb : (SQJ)); \
        }                                                                       \
    } while (0)

    for (int jt = 0; jt < NTILE; jt += 2) {
        MFMA_TILE(bA, tA, sqA, labA);
        if (jt + 2 < NTILE) {   // prefetch tile jt+2 into the A slot
            const __hip_bfloat16* bp = bbase + (size_t)(jt + 2) * 2048;
            #pragma unroll
            for (int kk = 0; kk < 4; ++kk)
                bA[kk] = *reinterpret_cast<const short8*>(bp + kk * 512);
            sqA  = sq[jstart + (jt + 2) * 16 + l15];
            labA = lab[jstart + (jt + 2) * 16 + l15];
        }
        MFMA_TILE(bB, tB, sqB, labB);
        if (jt + 3 < NTILE) {   // prefetch tile jt+3 into the B slot
            const __hip_bfloat16* bp = bbase + (size_t)(jt + 3) * 2048;
            #pragma unroll
            for (int kk = 0; kk < 4; ++kk)
                bB[kk] = *reinterpret_cast<const short8*>(bp + kk * 512);
            sqB  = sq[jstart + (jt + 3) * 16 + l15];
            labB = lab[jstart + (jt + 3) * 16 + l15];
        }
        #pragma unroll
        for (int s = 0; s < 4; ++s)
            #pragma unroll
            for (int q = 0; q < 4; ++q) {
                mx[s][q] = fmaxf(fmaxf(mx[s][q], tA[s][q]), tB[s][q]);
                mn[s][q] = fminf(fminf(mn[s][q], tA[s][q]), tB[s][q]);
            }
    }
    #undef MFMA_TILE

    // reduce over the 16 cols held by the 16 lanes of each g-group
    #pragma unroll
    for (int s = 0; s < 4; ++s)
        #pragma unroll
        for (int q = 0; q < 4; ++q) {
            #pragma unroll
            for (int mk = 1; mk < 16; mk <<= 1) {
                mx[s][q] = fmaxf(mx[s][q], __shfl_xor(mx[s][q], mk, 64));
                mn[s][q] = fminf(mn[s][q], __shfl_xor(mn[s][q], mk, 64));
            }
        }
    if (l15 == 0) {
        #pragma unroll
        for (int s = 0; s < 4; ++s)
            #pragma unroll
            for (int q = 0; q < 4; ++q) {
                const int i = rowbase + s * 16 + g * 4 + q;
                const float sqi = sq[i];
                atomicMax(&kp[i], __float_as_int(sqi + mx[s][q] + KOFF));
                atomicMin(&kn[i], __float_as_int(sqi + mn[s][q] + KOFF));
            }
    }

    // ---- last-block combine (done-counter; atomic reads are device-coherent) ----
    __shared__ int isLast;
    __shared__ float sv[4];
    if (tid == 0) {
        __threadfence();
        isLast = (atomicAdd(done, 1) == NBLK - 1);
    }
    __syncthreads();
    if (!isLast) return;

    float sum = 0.f;
    for (int r = tid; r < B_ROWS; r += 256) {
        const float hp2 = __int_as_float(atomicMax(&kp[r], 0)) - BIAS - KOFF;
        const float hn2 = __int_as_float(atomicMin(&kn[r], 0x7F7F7F7F)) - KOFF;
        sum += fmaxf(sqrtf(fmaxf(hp2, 0.f)) - sqrtf(fmaxf(hn2, 0.f)) + 1.0f, 0.f);
    }
    #pragma unroll
    for (int mk = 1; mk < 64; mk <<= 1) sum += __shfl_xor(sum, mk, 64);
    if (lane == 0) sv[wave] = sum;
    __syncthreads();
    if (tid == 0) out[0] = (sv[0] + sv[1] + sv[2] + sv[3]) / (float)B_ROWS;
}

// ---------------- launch ----------------
extern "C" void kernel_launch(void* const* d_in, const int* in_sizes, int n_in,
                              void* d_out, int out_size, void* d_ws, size_t ws_size,
                              hipStream_t stream) {
    const float* x   = (const float*)d_in[0];
    const int*   lab = (const int*)d_in[1];
    float*       out = (float*)d_out;

    char* ws = (char*)d_ws;
    __hip_bfloat16* xf = (__hip_bfloat16*)ws;
    float* sq   = (float*)(ws + OFF_SQ);
    int*   kp   = (int*)(ws + OFF_KP);
    int*   kn   = (int*)(ws + OFF_KN);
    int*   done = (int*)(ws + OFF_ACC);

    prep_kernel<<<B_ROWS / 4, 256, 0, stream>>>(x, xf, sq, kp, kn, done);
    main_kernel<<<dim3(NRB, NSPLIT), 256, 0, stream>>>(xf, sq, lab, kp, kn, done, out);
}